// Round 5
// baseline (159.505 us; speedup 1.0000x reference)
//
#include <hip/hip_runtime.h>
#include <math.h>
#include <float.h>

// Problem constants: B=4, S=2048, DIN=1024, DOUT=1024, E=16, K=2
#define DIN_  1024
#define DOUT_ 1024
#define NE    16
#define KK    2
#define NTOK  8192

// ws layout: [0,128KB): float wc[E][K][DIN] compact expert columns

// ---------------------------------------------------------------------------
// Kernel A: compact expert_w columns j=0,1 into Wc[e][j][d]. 128 KB.
// ---------------------------------------------------------------------------
__global__ __launch_bounds__(256) void compact_w_kernel(
    const float* __restrict__ ew,   // [E, DIN, DOUT]
    float* __restrict__ wc)         // [E, K, DIN]
{
    int i = blockIdx.x * 256 + threadIdx.x;   // over NE*KK*DIN = 32768
    if (i >= NE * KK * DIN_) return;
    int d = i & (DIN_ - 1);
    int j = (i >> 10) & 1;
    int e = i >> 11;
    wc[i] = ew[(size_t)e * DIN_ * DOUT_ + (size_t)d * DOUT_ + j];
}

// ---------------------------------------------------------------------------
// Wave-autonomous fused kernel: one wave = 2 tokens, NO barriers, NO LDS.
// Per lane: 8 float4 of x (both tokens), 2x16 gate accumulators.
// Butterfly-reduce -> every lane has all 16 totals -> redundant top-2
// (static-indexed predicated loops, no scratch) -> expert dots reuse x regs.
// ---------------------------------------------------------------------------
__global__ __launch_bounds__(256) void moe_wave_kernel(
    const float* __restrict__ x,        // [NTOK, DIN]
    const float* __restrict__ gate_w,   // [DIN, E]
    const float* __restrict__ gate_b,   // [E]
    const float* __restrict__ ebias,    // [E]
    const float* __restrict__ wc,       // [E, K, DIN]
    const float* __restrict__ expert_b, // [E, DOUT]
    float* __restrict__ out_final,      // [NTOK, DOUT]
    float* __restrict__ out_probs,      // [NTOK, E]
    float* __restrict__ out_idx,        // [NTOK, K] as float
    int write_aux)
{
    const int lane = threadIdx.x & 63;
    const int wid  = threadIdx.x >> 6;                // 0..3
    const int tok0 = (blockIdx.x * 4 + wid) * 2;
    const int tok1 = tok0 + 1;

    // ---- x rows into registers (kept for both phases), fully coalesced ---
    const float4* x0p = (const float4*)(x + (size_t)tok0 * DIN_);
    const float4* x1p = (const float4*)(x + (size_t)tok1 * DIN_);
    float4 xr0[4], xr1[4];
#pragma unroll
    for (int c = 0; c < 4; c++) {
        xr0[c] = x0p[c * 64 + lane];
        xr1[c] = x1p[c * 64 + lane];
    }

    // ---- gating: lane covers d = c*256 + 4*lane + j ----------------------
    const float4* gw4 = (const float4*)gate_w;        // row d = 4 float4
    float a0[NE], a1[NE];
#pragma unroll
    for (int e = 0; e < NE; e++) { a0[e] = 0.f; a1[e] = 0.f; }

#pragma unroll
    for (int c = 0; c < 4; c++) {
#pragma unroll
        for (int j = 0; j < 4; j++) {
            int r = c * 256 + 4 * lane + j;
            float4 g0 = gw4[r * 4 + 0];
            float4 g1 = gw4[r * 4 + 1];
            float4 g2 = gw4[r * 4 + 2];
            float4 g3 = gw4[r * 4 + 3];
            float xs0 = (j == 0) ? xr0[c].x : (j == 1) ? xr0[c].y : (j == 2) ? xr0[c].z : xr0[c].w;
            float xs1 = (j == 0) ? xr1[c].x : (j == 1) ? xr1[c].y : (j == 2) ? xr1[c].z : xr1[c].w;
            a0[0]  += xs0 * g0.x; a0[1]  += xs0 * g0.y; a0[2]  += xs0 * g0.z; a0[3]  += xs0 * g0.w;
            a0[4]  += xs0 * g1.x; a0[5]  += xs0 * g1.y; a0[6]  += xs0 * g1.z; a0[7]  += xs0 * g1.w;
            a0[8]  += xs0 * g2.x; a0[9]  += xs0 * g2.y; a0[10] += xs0 * g2.z; a0[11] += xs0 * g2.w;
            a0[12] += xs0 * g3.x; a0[13] += xs0 * g3.y; a0[14] += xs0 * g3.z; a0[15] += xs0 * g3.w;
            a1[0]  += xs1 * g0.x; a1[1]  += xs1 * g0.y; a1[2]  += xs1 * g0.z; a1[3]  += xs1 * g0.w;
            a1[4]  += xs1 * g1.x; a1[5]  += xs1 * g1.y; a1[6]  += xs1 * g1.z; a1[7]  += xs1 * g1.w;
            a1[8]  += xs1 * g2.x; a1[9]  += xs1 * g2.y; a1[10] += xs1 * g2.z; a1[11] += xs1 * g2.w;
            a1[12] += xs1 * g3.x; a1[13] += xs1 * g3.y; a1[14] += xs1 * g3.z; a1[15] += xs1 * g3.w;
        }
    }

    // ---- 64-lane butterfly: every lane gets full totals ------------------
#pragma unroll
    for (int e = 0; e < NE; e++) {
        float v0 = a0[e], v1 = a1[e];
#pragma unroll
        for (int m = 32; m >= 1; m >>= 1) {
            v0 += __shfl_xor(v0, m, 64);
            v1 += __shfl_xor(v1, m, 64);
        }
        float gb = gate_b[e];
        a0[e] = v0 + gb;              // gate_output (pre-sigmoid)
        a1[e] = v1 + gb;
    }

    float eb[NE];
#pragma unroll
    for (int e = 0; e < NE; e++) eb[e] = ebias[e];

    // ---- top-2 per token, redundantly on every lane (static indices) -----
    int i00 = 0, i01 = 0, i10 = 0, i11 = 0;
    float w00, w01, w10, w11;
    {
        float best = a0[0] + eb[0], bgo = a0[0];
#pragma unroll
        for (int e = 1; e < NE; e++) {
            float lg = a0[e] + eb[e];
            if (lg > best) { best = lg; bgo = a0[e]; i00 = e; }
        }
        float best2 = -FLT_MAX, bgo2 = 0.f;
#pragma unroll
        for (int e = 0; e < NE; e++) {
            float lg = a0[e] + eb[e];
            bool c = (e != i00) && (lg > best2);
            if (c) { best2 = lg; bgo2 = a0[e]; i01 = e; }
        }
        float p0 = 1.f / (1.f + expf(-bgo));
        float p1 = 1.f / (1.f + expf(-bgo2));
        float inv = 1.f / (p0 + p1);
        w00 = p0 * inv; w01 = p1 * inv;
    }
    {
        float best = a1[0] + eb[0], bgo = a1[0];
#pragma unroll
        for (int e = 1; e < NE; e++) {
            float lg = a1[e] + eb[e];
            if (lg > best) { best = lg; bgo = a1[e]; i10 = e; }
        }
        float best2 = -FLT_MAX, bgo2 = 0.f;
#pragma unroll
        for (int e = 0; e < NE; e++) {
            float lg = a1[e] + eb[e];
            bool c = (e != i10) && (lg > best2);
            if (c) { best2 = lg; bgo2 = a1[e]; i11 = e; }
        }
        float p0 = 1.f / (1.f + expf(-bgo));
        float p1 = 1.f / (1.f + expf(-bgo2));
        float inv = 1.f / (p0 + p1);
        w10 = p0 * inv; w11 = p1 * inv;
    }

    // ---- aux outputs (probs lanes 0..31 coalesced; idx lanes 0/1) --------
    if (write_aux) {
        int esel = lane & 15;
        float sg0 = 0.f, sg1 = 0.f;
#pragma unroll
        for (int e = 0; e < NE; e++) {
            bool m = (esel == e);
            sg0 = m ? a0[e] : sg0;
            sg1 = m ? a1[e] : sg1;
        }
        if (lane < 32) {
            int   t  = (lane < 16) ? tok0 : tok1;
            float sg = (lane < 16) ? sg0 : sg1;
            out_probs[(size_t)t * NE + esel] = 1.f / (1.f + expf(-sg));
        }
        if (lane == 0) {
            out_idx[(size_t)tok0 * KK + 0] = (float)i00;
            out_idx[(size_t)tok0 * KK + 1] = (float)i01;
        }
        if (lane == 1) {
            out_idx[(size_t)tok1 * KK + 0] = (float)i10;
            out_idx[(size_t)tok1 * KK + 1] = (float)i11;
        }
    }

    // ---- expert dots: reuse x registers, wc coalesced (L2-hot) -----------
    const float4* w0a = (const float4*)(wc + ((size_t)i00 * KK + 0) * DIN_);
    const float4* w0b = (const float4*)(wc + ((size_t)i01 * KK + 1) * DIN_);
    const float4* w1a = (const float4*)(wc + ((size_t)i10 * KK + 0) * DIN_);
    const float4* w1b = (const float4*)(wc + ((size_t)i11 * KK + 1) * DIN_);
    float d00 = 0.f, d01 = 0.f, d10 = 0.f, d11 = 0.f;
#pragma unroll
    for (int c = 0; c < 4; c++) {
        float4 p = w0a[c * 64 + lane];
        float4 q = w0b[c * 64 + lane];
        float4 u = w1a[c * 64 + lane];
        float4 v = w1b[c * 64 + lane];
        d00 += xr0[c].x * p.x + xr0[c].y * p.y + xr0[c].z * p.z + xr0[c].w * p.w;
        d01 += xr0[c].x * q.x + xr0[c].y * q.y + xr0[c].z * q.z + xr0[c].w * q.w;
        d10 += xr1[c].x * u.x + xr1[c].y * u.y + xr1[c].z * u.z + xr1[c].w * u.w;
        d11 += xr1[c].x * v.x + xr1[c].y * v.y + xr1[c].z * v.z + xr1[c].w * v.w;
    }
#pragma unroll
    for (int m = 32; m >= 1; m >>= 1) {
        d00 += __shfl_xor(d00, m, 64);
        d01 += __shfl_xor(d01, m, 64);
        d10 += __shfl_xor(d10, m, 64);
        d11 += __shfl_xor(d11, m, 64);
    }
    float f0 = w00 * (d00 + expert_b[(size_t)i00 * DOUT_ + 0])
             + w01 * (d01 + expert_b[(size_t)i01 * DOUT_ + 1]);
    float f1 = w10 * (d10 + expert_b[(size_t)i10 * DOUT_ + 0])
             + w11 * (d11 + expert_b[(size_t)i11 * DOUT_ + 1]);

    // ---- broadcast stores, fully coalesced -------------------------------
    float4 f0v = make_float4(f0, f0, f0, f0);
    float4 f1v = make_float4(f1, f1, f1, f1);
    float4* o0 = (float4*)(out_final + (size_t)tok0 * DOUT_);
    float4* o1 = (float4*)(out_final + (size_t)tok1 * DOUT_);
#pragma unroll
    for (int c = 0; c < 4; c++) {
        o0[c * 64 + lane] = f0v;
        o1[c * 64 + lane] = f1v;
    }
}

// ---------------------------------------------------------------------------
extern "C" void kernel_launch(void* const* d_in, const int* in_sizes, int n_in,
                              void* d_out, int out_size, void* d_ws, size_t ws_size,
                              hipStream_t stream) {
    const float* x        = (const float*)d_in[0];
    const float* gate_w   = (const float*)d_in[1];
    const float* gate_b   = (const float*)d_in[2];
    const float* expert_w = (const float*)d_in[3];
    const float* expert_b = (const float*)d_in[4];
    const float* ebias    = (const float*)d_in[5];
    float* out = (float*)d_out;

    float* wc = (float*)d_ws;   // 128 KB compact expert columns

    float* out_final = out;
    float* out_probs = out + (size_t)NTOK * DOUT_;
    float* out_idx   = out_probs + (size_t)NTOK * NE;
    int write_aux = (out_size >= NTOK * DOUT_ + NTOK * NE + NTOK * KK) ? 1 : 0;

    compact_w_kernel<<<(NE * KK * DIN_ + 255) / 256, 256, 0, stream>>>(expert_w, wc);
    // 8 tokens per block (2 per wave) -> 1024 blocks
    moe_wave_kernel<<<NTOK / 8, 256, 0, stream>>>(
        x, gate_w, gate_b, ebias, wc, expert_b,
        out_final, out_probs, out_idx, write_aux);
}